// Round 12
// baseline (285.491 us; speedup 1.0000x reference)
//
#include <hip/hip_runtime.h>

#define N_NODES 100000
#define N_EDGES 1200000
#define D 64
#define KEEP_PROB 0.7f
#define INV_KEEP (1.0f / KEEP_PROB)
#define NBUCK 1564         // ceil(N_NODES / 64) row-range buckets (row >> 6)
#define MAXB 1024          // finalize LDS record capacity (mean ~767)
#define PPART 256          // partition/hist blocks (contiguous chunks)
#define CHUNK4 1172        // ceil((N_EDGES/4) / PPART) int4-edges per block
#define NB64 ((NBUCK + 63) / 64)   // 25 blocks for sum/rebase

#define ALOAD_I(p)   __hip_atomic_load((p), __ATOMIC_RELAXED, __HIP_MEMORY_SCOPE_AGENT)
#define ALOAD_U64(p) __hip_atomic_load((p), __ATOMIC_RELAXED, __HIP_MEMORY_SCOPE_AGENT)

// ---------------------------------------------------------------------------
// SESSION LEDGER (hardware-verified):
//   R6: per-edge fp LDS atomicAdd in spmm hot loop = ~3.6 CU-cyc/lane-op
//       -> 455us/layer. NEVER use fp LDS atomics per-element.
//   R9: folding the row-sort into spmm (29.7KB LDS) dropped occupancy
//       53%->32% -> 60.7us/layer. Keep spmm LDS small.
//   R10: fusing fc into spmm-0's epilogue spilled (VGPR_Count=64, epilogue
//       needs ~100 live) -> 634MB scratch writes, 338us. Keep fc separate.
//   R11: R8 structure reproduced at 270.7us. spmm is LATENCY-bound:
//       7.6 GB/s/CU, ~410 cyc/edge-step/chain -> this round: 32 chains.
// ---------------------------------------------------------------------------
__global__ __launch_bounds__(256) void zero_kernel(float4* __restrict__ p, int n4) {
    int i = blockIdx.x * 256 + threadIdx.x;
    if (i < n4) p[i] = make_float4(0.f, 0.f, 0.f, 0.f);
}

// ---------------------------------------------------------------------------
// Build 1: per-block bucket histogram over CONTIGUOUS chunks (same
// decomposition as partition_kernel). Writes ONLY h[p][b] (coalesced).
__global__ __launch_bounds__(256) void bucket_hist_kernel(const int4* __restrict__ rows4,
                                                          int* __restrict__ h) {
    __shared__ int hh[NBUCK];
    int p = blockIdx.x;
    int t = threadIdx.x;
    for (int i = t; i < NBUCK; i += 256) hh[i] = 0;
    __syncthreads();
    int i0 = p * CHUNK4;
    int i1 = i0 + CHUNK4;
    if (i1 > N_EDGES / 4) i1 = N_EDGES / 4;
    for (int i = i0 + t; i < i1; i += 256) {
        int4 r = rows4[i];
        atomicAdd(&hh[r.x >> 6], 1);
        atomicAdd(&hh[r.y >> 6], 1);
        atomicAdd(&hh[r.z >> 6], 1);
        atomicAdd(&hh[r.w >> 6], 1);
    }
    __syncthreads();
    int* hp = h + p * NBUCK;
    for (int i = t; i < NBUCK; i += 256) hp[i] = hh[i];
}

// ---------------------------------------------------------------------------
// Build 1.5: total[b] = sum_p h[p][b]. 64 buckets/block, 4 chunk-threads.
__global__ __launch_bounds__(256) void sum_kernel(const int* __restrict__ h,
                                                  int* __restrict__ total) {
    __shared__ int sq[4][64];
    int t = threadIdx.x;
    int bo = t & 63, q = t >> 6;
    int b = blockIdx.x * 64 + bo;
    int s = 0;
    if (b < NBUCK) {
        for (int p = q * 64; p < q * 64 + 64; ++p) s += h[p * NBUCK + b];
    }
    sq[q][bo] = s;
    __syncthreads();
    if (q == 0 && b < NBUCK)
        total[b] = sq[0][bo] + sq[1][bo] + sq[2][bo] + sq[3][bo];
}

// ---------------------------------------------------------------------------
// Build 2: single-block exclusive scan of dense totals -> bbase.
__global__ __launch_bounds__(256) void bucket_scan_kernel(const int* __restrict__ total,
                                                          int* __restrict__ bbase) {
    __shared__ int part[256];
    const int CH = 7;   // 256*7 = 1792 >= NBUCK
    int t = threadIdx.x;
    int e[CH]; int s = 0;
    #pragma unroll
    for (int k = 0; k < CH; ++k) {
        int j = t * CH + k;
        e[k] = (j < NBUCK) ? total[j] : 0;
        s += e[k];
    }
    part[t] = s;
    __syncthreads();
    for (int d = 1; d < 256; d <<= 1) {
        int w = (t >= d) ? part[t - d] : 0;
        __syncthreads();
        part[t] += w;
        __syncthreads();
    }
    int run = part[t] - s;
    #pragma unroll
    for (int k = 0; k < CH; ++k) {
        int j = t * CH + k;
        if (j < NBUCK) { bbase[j] = run; run += e[k]; }
    }
    if (t == 255) bbase[NBUCK] = run;            // == N_EDGES
}

// ---------------------------------------------------------------------------
// Build 2.5: h[p][b] <- bbase[b] + sum_{q<p} h[q][b]. 64 buckets/block,
// 4 chunk-threads per bucket: chunk sums -> LDS combine -> rewrite.
__global__ __launch_bounds__(256) void rebase_kernel(int* __restrict__ h,
                                                     const int* __restrict__ bbase) {
    __shared__ int sq[4][64];
    int t = threadIdx.x;
    int bo = t & 63, q = t >> 6;
    int b = blockIdx.x * 64 + bo;
    bool ok = (b < NBUCK);
    int s = 0;
    if (ok) {
        for (int p = q * 64; p < q * 64 + 64; ++p) s += h[p * NBUCK + b];
    }
    sq[q][bo] = s;
    __syncthreads();
    if (ok) {
        int run = bbase[b];
        for (int qq = 0; qq < q; ++qq) run += sq[qq][bo];
        for (int p = q * 64; p < q * 64 + 64; ++p) {
            int idx = p * NBUCK + b;
            int c = h[idx];
            h[idx] = run;
            run += c;
        }
    }
}

// ---------------------------------------------------------------------------
// Build 3 (R8-proven): partition edges into buckets. Staging record
// (col, v0, v1, row) lands in the x1 region (dead until spmm layer 0).
__global__ __launch_bounds__(256) void partition_kernel(
    const int4*   __restrict__ rows4,
    const int4*   __restrict__ cols4,
    const float4* __restrict__ vals4,
    const float4* __restrict__ u04,
    const float4* __restrict__ u14,
    const int*    __restrict__ h,
    uint4*        __restrict__ staging) {
    __shared__ int cur[NBUCK];
    int p = blockIdx.x;
    int t = threadIdx.x;
    const int* hp = h + p * NBUCK;
    for (int i = t; i < NBUCK; i += 256) cur[i] = hp[i];
    __syncthreads();

    int i0 = p * CHUNK4;
    int i1 = i0 + CHUNK4;
    if (i1 > N_EDGES / 4) i1 = N_EDGES / 4;
    for (int i = i0 + t; i < i1; i += 256) {
        int4   r  = rows4[i];
        int4   c  = cols4[i];
        float4 v  = vals4[i];
        float4 u0 = u04[i];
        float4 u1 = u14[i];

        int p0 = atomicAdd(&cur[r.x >> 6], 1);
        int p1 = atomicAdd(&cur[r.y >> 6], 1);
        int p2 = atomicAdd(&cur[r.z >> 6], 1);
        int p3 = atomicAdd(&cur[r.w >> 6], 1);

        uint4 rec; float vv;
        vv = v.x * INV_KEEP;
        rec.x = (unsigned)c.x;
        rec.y = __float_as_uint((u0.x + KEEP_PROB >= 1.0f) ? vv : 0.f);
        rec.z = __float_as_uint((u1.x + KEEP_PROB >= 1.0f) ? vv : 0.f);
        rec.w = (unsigned)r.x;
        staging[p0] = rec;
        vv = v.y * INV_KEEP;
        rec.x = (unsigned)c.y;
        rec.y = __float_as_uint((u0.y + KEEP_PROB >= 1.0f) ? vv : 0.f);
        rec.z = __float_as_uint((u1.y + KEEP_PROB >= 1.0f) ? vv : 0.f);
        rec.w = (unsigned)r.y;
        staging[p1] = rec;
        vv = v.z * INV_KEEP;
        rec.x = (unsigned)c.z;
        rec.y = __float_as_uint((u0.z + KEEP_PROB >= 1.0f) ? vv : 0.f);
        rec.z = __float_as_uint((u1.z + KEEP_PROB >= 1.0f) ? vv : 0.f);
        rec.w = (unsigned)r.z;
        staging[p2] = rec;
        vv = v.w * INV_KEEP;
        rec.x = (unsigned)c.w;
        rec.y = __float_as_uint((u0.w + KEEP_PROB >= 1.0f) ? vv : 0.f);
        rec.z = __float_as_uint((u1.w + KEEP_PROB >= 1.0f) ? vv : 0.f);
        rec.w = (unsigned)r.w;
        staging[p3] = rec;
    }
}

// ---------------------------------------------------------------------------
// Build 4 (R8-proven): one block per bucket. Sort by row, output SoA
// per-layer 8-B records (col|lr<<17, v) into ed0/ed1.
__global__ __launch_bounds__(256) void finalize_kernel(
    const uint4* __restrict__ staging,
    const int*   __restrict__ bbase,
    unsigned long long* __restrict__ ed0,
    unsigned long long* __restrict__ ed1) {
    __shared__ uint4 recs[MAXB];
    __shared__ int cnt[64], cur[64], part[64];
    int b = blockIdx.x;
    int t = threadIdx.x;
    int base = bbase[b];
    int size = bbase[b + 1] - base;
    bool small = (size <= MAXB);

    if (small) {
        for (int i = t; i < size; i += 256) recs[i] = staging[base + i];
    }
    if (t < 64) cnt[t] = 0;
    __syncthreads();

    for (int i = t; i < size; i += 256) {
        unsigned rw = small ? recs[i].w : staging[base + i].w;
        atomicAdd(&cnt[rw & 63], 1);
    }
    __syncthreads();

    int v = (t < 64) ? cnt[t] : 0;
    if (t < 64) part[t] = v;
    __syncthreads();
    for (int d = 1; d < 64; d <<= 1) {
        int w = (t >= d && t < 64) ? part[t - d] : 0;
        __syncthreads();
        if (t < 64) part[t] += w;
        __syncthreads();
    }
    if (t < 64) cur[t] = part[t] - v;
    __syncthreads();

    for (int i = t; i < size; i += 256) {
        uint4 r = small ? recs[i] : staging[base + i];
        unsigned lr = r.w & 63u;
        int slot = base + atomicAdd(&cur[lr], 1);
        unsigned cr = r.x | (lr << 17);     // pack local row into col word
        ed0[slot] = ((unsigned long long)r.y << 32) | cr;
        ed1[slot] = ((unsigned long long)r.z << 32) | cr;
    }
}

// ---------------------------------------------------------------------------
// SpMM: flat-balanced register-accumulation, 32 chains (was 16).
// R11 diagnosis: latency-bound at ~410 cyc/edge-step/chain (7.6 GB/s/CU,
// VALUBusy 15%). 32 slices x 8-lane groups halve serial steps per chain;
// each lane covers its row-half via two float4 gathers (same row fetch).
// Ownership protocol unchanged: register accumulate + plain LDS store on
// row change; slice-boundary prefixes to partb, merged after barrier.
// No LDS atomics in hot loop (R6). LDS 24.6KB -> 6 blocks/CU (R9 guard).
__global__ __launch_bounds__(256) void spmm_flat_kernel(
    const float4* __restrict__ x_in,
    const unsigned long long* __restrict__ ed,
    const int*   __restrict__ bbase,
    float4*      __restrict__ io,
    int layer) {
    __shared__ float accs[64 * 64];   // 16 KB: [lr][col]
    __shared__ float partb[32][64];   // 8 KB: boundary-prefix partials
    __shared__ int   prow[32];
    int b = blockIdx.x;
    int t = threadIdx.x;
    int base = bbase[b];
    int size = bbase[b + 1] - base;
    int row0 = b << 6;

    #pragma unroll
    for (int i = 0; i < 4; ++i)
        *(float4*)&accs[(i * 256 + t) * 4] = make_float4(0.f, 0.f, 0.f, 0.f);
    if (t < 32) prow[t] = -1;
    __syncthreads();

    int g  = t >> 3;                  // slice 0..31
    int l8 = t & 7;
    int e0 = base + ((size * g) >> 5);
    int e1 = base + ((size * (g + 1)) >> 5);
    int j0 = l8 << 2;                 // cols j0..j0+3 and j0+32..j0+35

    // does this slice start mid-row? (prev record has same lr)
    bool partial = false;
    if (e0 < e1 && e0 > base) {
        unsigned plo = (unsigned)ALOAD_U64(&ed[e0 - 1]);
        unsigned flo = (unsigned)ALOAD_U64(&ed[e0]);
        partial = ((plo >> 17) == (flo >> 17));
    }

    float4 a0 = make_float4(0.f, 0.f, 0.f, 0.f);
    float4 a1 = make_float4(0.f, 0.f, 0.f, 0.f);
    int cur = -1;
    bool first = true;
    for (int e = e0; e < e1; ++e) {
        unsigned long long rec = ALOAD_U64(&ed[e]);
        unsigned lo = (unsigned)rec;
        float v = __uint_as_float((unsigned)(rec >> 32));
        int lr = (int)(lo >> 17);
        if (lr != cur) {                       // group-uniform branch
            if (cur >= 0) {
                if (first && partial) {
                    *(float4*)&partb[g][j0] = a0;
                    *(float4*)&partb[g][j0 + 32] = a1;
                    if (l8 == 0) prow[g] = cur;
                } else {
                    *(float4*)&accs[(cur << 6) + j0] = a0;        // owned row
                    *(float4*)&accs[(cur << 6) + j0 + 32] = a1;
                }
                first = false;
            }
            a0 = make_float4(0.f, 0.f, 0.f, 0.f);
            a1 = make_float4(0.f, 0.f, 0.f, 0.f);
            cur = lr;
        }
        int c  = (int)(lo & 0x1ffffu);
        int cc = (v != 0.f) ? c : 0;          // dropped edges -> hot row 0
        float4 x0 = x_in[(cc << 4) + l8];
        float4 x1v = x_in[(cc << 4) + 8 + l8];
        a0.x = fmaf(v, x0.x, a0.x);
        a0.y = fmaf(v, x0.y, a0.y);
        a0.z = fmaf(v, x0.z, a0.z);
        a0.w = fmaf(v, x0.w, a0.w);
        a1.x = fmaf(v, x1v.x, a1.x);
        a1.y = fmaf(v, x1v.y, a1.y);
        a1.z = fmaf(v, x1v.z, a1.z);
        a1.w = fmaf(v, x1v.w, a1.w);
    }
    if (cur >= 0) {                            // tail flush
        if (first && partial) {
            *(float4*)&partb[g][j0] = a0;
            *(float4*)&partb[g][j0 + 32] = a1;
            if (l8 == 0) prow[g] = cur;
        } else {
            *(float4*)&accs[(cur << 6) + j0] = a0;
            *(float4*)&accs[(cur << 6) + j0 + 32] = a1;
        }
    }
    __syncthreads();

    // merge boundary partials: 64 threads (one col each), serial over slices
    if (t < 64) {
        for (int gg = 1; gg < 32; ++gg) {
            int pr = prow[gg];
            if (pr >= 0) accs[(pr << 6) + t] += partb[gg][t];
        }
    }
    __syncthreads();

    // writeback: 1024 float4 granules, coalesced
    #pragma unroll
    for (int i = 0; i < 4; ++i) {
        int idx = i * 256 + t;        // 0..1023
        int lr = idx >> 4;
        int gg = idx & 15;
        int row = row0 + lr;
        if (row < N_NODES) {
            float4 sv = *(const float4*)&accs[(lr << 6) + (gg << 2)];
            int o = (row << 4) + gg;
            if (layer == 0) {
                io[o] = sv;
            } else {
                float4 p = io[o];
                p.x = (p.x + sv.x) * (1.0f / 3.0f);
                p.y = (p.y + sv.y) * (1.0f / 3.0f);
                p.z = (p.z + sv.z) * (1.0f / 3.0f);
                p.w = (p.w + sv.w) * (1.0f / 3.0f);
                io[o] = p;
            }
        }
    }
}

// ---------------------------------------------------------------------------
// out[n,j] = b[j] + sum_k emb[n,k]*W[j,k] + x1[n,j]
// Register-blocked: 64 nodes/block, 4x4 tile/thread; launch_bounds(256,4)
// caps VGPR at 128 (R3 lesson). R10 lesson: keep SEPARATE from spmm.
#define FMA4(A, E, WV) \
    A.x = fmaf(E, WV.x, A.x); A.y = fmaf(E, WV.y, A.y); \
    A.z = fmaf(E, WV.z, A.z); A.w = fmaf(E, WV.w, A.w);

__global__ __launch_bounds__(256, 4) void fc_add_kernel(
    const float* __restrict__ emb,
    const float* __restrict__ W,
    const float* __restrict__ b,
    const float* __restrict__ x1,
    float*       __restrict__ out) {
    __shared__ float Wt[D * 68];    // Wt[k][j] = W[j][k], row pad 68
    __shared__ float Es[64 * 68];   // Es[n][k],           row pad 68

    int t = threadIdx.x;
    int n0 = blockIdx.x * 64;

    #pragma unroll
    for (int i = 0; i < 16; ++i) {
        int idx = i * 256 + t;          // = j*64 + k
        Wt[(idx & 63) * 68 + (idx >> 6)] = W[idx];
    }
    #pragma unroll
    for (int i = 0; i < 4; ++i) {
        int idx4 = i * 256 + t;
        int n = idx4 >> 4;              // 0..63
        int k0 = (idx4 & 15) * 4;
        float4 v = make_float4(0.f, 0.f, 0.f, 0.f);
        if (n0 + n < N_NODES) v = *(const float4*)&emb[(n0 + n) * D + k0];
        *(float4*)&Es[n * 68 + k0] = v;
    }
    __syncthreads();

    int tj = t & 15;                    // j-group: j0 = 4*tj
    int tn = t >> 4;                    // node-group: nodes 4*tn .. 4*tn+3
    int j0 = tj * 4;

    float4 bb = *(const float4*)&b[j0];
    float4 acc[4];
    #pragma unroll
    for (int i = 0; i < 4; ++i) acc[i] = bb;

    const float* es = &Es[(tn * 4) * 68];
    #pragma unroll 4
    for (int kc = 0; kc < 16; ++kc) {
        int k = kc * 4;
        float4 w0 = *(const float4*)&Wt[(k + 0) * 68 + j0];
        float4 w1 = *(const float4*)&Wt[(k + 1) * 68 + j0];
        float4 w2 = *(const float4*)&Wt[(k + 2) * 68 + j0];
        float4 w3 = *(const float4*)&Wt[(k + 3) * 68 + j0];
        float4 e0 = *(const float4*)&es[0 * 68 + k];
        float4 e1 = *(const float4*)&es[1 * 68 + k];
        float4 e2 = *(const float4*)&es[2 * 68 + k];
        float4 e3 = *(const float4*)&es[3 * 68 + k];
        FMA4(acc[0], e0.x, w0); FMA4(acc[0], e0.y, w1);
        FMA4(acc[0], e0.z, w2); FMA4(acc[0], e0.w, w3);
        FMA4(acc[1], e1.x, w0); FMA4(acc[1], e1.y, w1);
        FMA4(acc[1], e1.z, w2); FMA4(acc[1], e1.w, w3);
        FMA4(acc[2], e2.x, w0); FMA4(acc[2], e2.y, w1);
        FMA4(acc[2], e2.z, w2); FMA4(acc[2], e2.w, w3);
        FMA4(acc[3], e3.x, w0); FMA4(acc[3], e3.y, w1);
        FMA4(acc[3], e3.z, w2); FMA4(acc[3], e3.w, w3);
    }

    #pragma unroll
    for (int i = 0; i < 4; ++i) {
        int n = n0 + tn * 4 + i;
        if (n < N_NODES) {
            float4 p = *(const float4*)&x1[n * D + j0];
            float4 a = acc[i];
            a.x += p.x; a.y += p.y; a.z += p.z; a.w += p.w;
            *(float4*)&out[n * D + j0] = a;
        }
    }
}

// ---------------------------------------------------------------------------
// Fallback (atomic path, replay-proven) if ws too small
__global__ __launch_bounds__(256) void spmm_atomic_kernel(
    const float* __restrict__ x_in,
    const float* __restrict__ vals,
    const float* __restrict__ drop_u,
    const int*   __restrict__ rows,
    const int*   __restrict__ cols,
    float*       __restrict__ x_out) {
    int wave = (blockIdx.x * 256 + threadIdx.x) >> 6;
    int lane = threadIdx.x & 63;
    if (wave >= N_EDGES) return;
    float u = drop_u[wave];
    if (u + KEEP_PROB < 1.0f) return;
    float v = vals[wave] * INV_KEEP;
    atomicAdd(&x_out[rows[wave] * D + lane], v * x_in[cols[wave] * D + lane]);
}

__global__ __launch_bounds__(256) void scale_kernel(float4* __restrict__ p, int n4) {
    int i = blockIdx.x * 256 + threadIdx.x;
    if (i < n4) {
        float4 v = p[i];
        v.x *= (1.f/3.f); v.y *= (1.f/3.f); v.z *= (1.f/3.f); v.w *= (1.f/3.f);
        p[i] = v;
    }
}

// ---------------------------------------------------------------------------
extern "C" void kernel_launch(void* const* d_in, const int* in_sizes, int n_in,
                              void* d_out, int out_size, void* d_ws, size_t ws_size,
                              hipStream_t stream) {
    const float* all_emb = (const float*)d_in[0];
    const float* W       = (const float*)d_in[1];
    const float* b       = (const float*)d_in[2];
    const float* vals    = (const float*)d_in[3];
    const float* drop_u  = (const float*)d_in[4];   // [2, E]
    const int*   rows    = (const int*)d_in[5];
    const int*   cols    = (const int*)d_in[6];

    float* out = (float*)d_out;

    // workspace layout (R8-proven):
    //   [0, 25.6M)       x1 output; staging records live in [0, 19.2M) and
    //                    h[PPART][NBUCK] at +19.2M (both dead before spmm-0
    //                    overwrites the region with x1)
    //   [26.0M, 35.6M)   ed0 — layer-0 SoA 8-B edge records
    //   [35.6M, 45.2M)   ed1 — layer-1 SoA 8-B edge records
    //   then total[], bbase[]
    char* ws = (char*)d_ws;
    float* x1       = (float*)(ws);
    uint4* staging  = (uint4*)(ws);
    int*   h        = (int*)  (ws + 19200000);            // 1,601,536 B
    unsigned long long* ed0 = (unsigned long long*)(ws + 26000064);  // 9.6 MB
    unsigned long long* ed1 = (unsigned long long*)(ws + 35600064);  // 9.6 MB
    int*   total    = (int*)  (ws + 45200064);            // 6,256 B
    int*   bbase    = (int*)  (ws + 45206320);            // 6,272 B
    const size_t WS_NEEDED = 45406528;   // unchanged (proven capacity)

    const int n4 = N_NODES * D / 4;
    const int zb = (n4 + 255) / 256;
    const int fc_blocks = (N_NODES + 63) / 64;            // 1563

    if (ws_size >= WS_NEEDED) {
        bucket_hist_kernel<<<PPART, 256, 0, stream>>>((const int4*)rows, h);
        sum_kernel<<<NB64, 256, 0, stream>>>(h, total);
        bucket_scan_kernel<<<1, 256, 0, stream>>>(total, bbase);
        rebase_kernel<<<NB64, 256, 0, stream>>>(h, bbase);
        partition_kernel<<<PPART, 256, 0, stream>>>(
            (const int4*)rows, (const int4*)cols, (const float4*)vals,
            (const float4*)drop_u, (const float4*)(drop_u + N_EDGES),
            h, staging);
        finalize_kernel<<<NBUCK, 256, 0, stream>>>(staging, bbase, ed0, ed1);
        // layer 0: x1 = A1 @ all_emb   (overwrites staging/h region)
        spmm_flat_kernel<<<NBUCK, 256, 0, stream>>>(
            (const float4*)all_emb, ed0, bbase, (float4*)x1, 0);
        // out = fc(all_emb) + x1
        fc_add_kernel<<<fc_blocks, 256, 0, stream>>>(all_emb, W, b, x1, out);
        // layer 1 (fused /3): out = (out + A2 @ x1) / 3
        spmm_flat_kernel<<<NBUCK, 256, 0, stream>>>(
            (const float4*)x1, ed1, bbase, (float4*)out, 1);
    } else {
        // fallback: proven atomic path
        const int spmm_blocks = (N_EDGES + 3) / 4;
        zero_kernel<<<zb, 256, 0, stream>>>((float4*)x1, n4);
        spmm_atomic_kernel<<<spmm_blocks, 256, 0, stream>>>(all_emb, vals, drop_u,
                                                            rows, cols, x1);
        fc_add_kernel<<<fc_blocks, 256, 0, stream>>>(all_emb, W, b, x1, out);
        spmm_atomic_kernel<<<spmm_blocks, 256, 0, stream>>>(x1, vals,
                                                            drop_u + N_EDGES,
                                                            rows, cols, out);
        scale_kernel<<<zb, 256, 0, stream>>>((float4*)out, n4);
    }
}

// Round 13
// 267.598 us; speedup vs baseline: 1.0669x; 1.0669x over previous
//
#include <hip/hip_runtime.h>

#define N_NODES 100000
#define N_EDGES 1200000
#define D 64
#define KEEP_PROB 0.7f
#define INV_KEEP (1.0f / KEEP_PROB)
#define NBUCK 1564         // ceil(N_NODES / 64) row-range buckets (row >> 6)
#define MAXB 1024          // finalize LDS record capacity (mean ~767)
#define PPART 256          // partition/hist blocks (contiguous chunks)
#define CHUNK4 1172        // ceil((N_EDGES/4) / PPART) int4-edges per block
#define NB64 ((NBUCK + 63) / 64)   // 25 blocks for sum/rebase

#define ALOAD_I(p)   __hip_atomic_load((p), __ATOMIC_RELAXED, __HIP_MEMORY_SCOPE_AGENT)
#define ALOAD_U64(p) __hip_atomic_load((p), __ATOMIC_RELAXED, __HIP_MEMORY_SCOPE_AGENT)

// ---------------------------------------------------------------------------
// SESSION LEDGER (hardware-verified):
//   R6:  per-edge fp LDS atomicAdd in spmm hot loop -> 455us/layer. Never.
//   R9:  29.7KB LDS spmm dropped occupancy 53->32% -> 60.7us/layer.
//   R10: fc fused into spmm epilogue spilled -> 634MB scratch, 338us.
//   R11: R8 structure = 270.7us. spmm latency-bound (7.6GB/s/CU, VALU 15%).
//   R12: 32 chains w/ 8-lane groups: FETCH +16% (locality loss) + occ 37%
//        -> 55.4us/layer. More chains must NOT change the fetch pattern.
//   R13 (this): direct-global row writeback, accs tile deleted: LDS 21->8.6KB
//        -> ~8 blocks/CU, identical gather pattern. Clean latency-theory test.
// ---------------------------------------------------------------------------
__global__ __launch_bounds__(256) void zero_kernel(float4* __restrict__ p, int n4) {
    int i = blockIdx.x * 256 + threadIdx.x;
    if (i < n4) p[i] = make_float4(0.f, 0.f, 0.f, 0.f);
}

// ---------------------------------------------------------------------------
// Build 1: per-block bucket histogram over CONTIGUOUS chunks (same
// decomposition as partition_kernel). Writes ONLY h[p][b] (coalesced).
__global__ __launch_bounds__(256) void bucket_hist_kernel(const int4* __restrict__ rows4,
                                                          int* __restrict__ h) {
    __shared__ int hh[NBUCK];
    int p = blockIdx.x;
    int t = threadIdx.x;
    for (int i = t; i < NBUCK; i += 256) hh[i] = 0;
    __syncthreads();
    int i0 = p * CHUNK4;
    int i1 = i0 + CHUNK4;
    if (i1 > N_EDGES / 4) i1 = N_EDGES / 4;
    for (int i = i0 + t; i < i1; i += 256) {
        int4 r = rows4[i];
        atomicAdd(&hh[r.x >> 6], 1);
        atomicAdd(&hh[r.y >> 6], 1);
        atomicAdd(&hh[r.z >> 6], 1);
        atomicAdd(&hh[r.w >> 6], 1);
    }
    __syncthreads();
    int* hp = h + p * NBUCK;
    for (int i = t; i < NBUCK; i += 256) hp[i] = hh[i];
}

// ---------------------------------------------------------------------------
// Build 1.5: total[b] = sum_p h[p][b]. 64 buckets/block, 4 chunk-threads.
__global__ __launch_bounds__(256) void sum_kernel(const int* __restrict__ h,
                                                  int* __restrict__ total) {
    __shared__ int sq[4][64];
    int t = threadIdx.x;
    int bo = t & 63, q = t >> 6;
    int b = blockIdx.x * 64 + bo;
    int s = 0;
    if (b < NBUCK) {
        for (int p = q * 64; p < q * 64 + 64; ++p) s += h[p * NBUCK + b];
    }
    sq[q][bo] = s;
    __syncthreads();
    if (q == 0 && b < NBUCK)
        total[b] = sq[0][bo] + sq[1][bo] + sq[2][bo] + sq[3][bo];
}

// ---------------------------------------------------------------------------
// Build 2: single-block exclusive scan of dense totals -> bbase.
__global__ __launch_bounds__(256) void bucket_scan_kernel(const int* __restrict__ total,
                                                          int* __restrict__ bbase) {
    __shared__ int part[256];
    const int CH = 7;   // 256*7 = 1792 >= NBUCK
    int t = threadIdx.x;
    int e[CH]; int s = 0;
    #pragma unroll
    for (int k = 0; k < CH; ++k) {
        int j = t * CH + k;
        e[k] = (j < NBUCK) ? total[j] : 0;
        s += e[k];
    }
    part[t] = s;
    __syncthreads();
    for (int d = 1; d < 256; d <<= 1) {
        int w = (t >= d) ? part[t - d] : 0;
        __syncthreads();
        part[t] += w;
        __syncthreads();
    }
    int run = part[t] - s;
    #pragma unroll
    for (int k = 0; k < CH; ++k) {
        int j = t * CH + k;
        if (j < NBUCK) { bbase[j] = run; run += e[k]; }
    }
    if (t == 255) bbase[NBUCK] = run;            // == N_EDGES
}

// ---------------------------------------------------------------------------
// Build 2.5: h[p][b] <- bbase[b] + sum_{q<p} h[q][b]. 64 buckets/block,
// 4 chunk-threads per bucket: chunk sums -> LDS combine -> rewrite.
__global__ __launch_bounds__(256) void rebase_kernel(int* __restrict__ h,
                                                     const int* __restrict__ bbase) {
    __shared__ int sq[4][64];
    int t = threadIdx.x;
    int bo = t & 63, q = t >> 6;
    int b = blockIdx.x * 64 + bo;
    bool ok = (b < NBUCK);
    int s = 0;
    if (ok) {
        for (int p = q * 64; p < q * 64 + 64; ++p) s += h[p * NBUCK + b];
    }
    sq[q][bo] = s;
    __syncthreads();
    if (ok) {
        int run = bbase[b];
        for (int qq = 0; qq < q; ++qq) run += sq[qq][bo];
        for (int p = q * 64; p < q * 64 + 64; ++p) {
            int idx = p * NBUCK + b;
            int c = h[idx];
            h[idx] = run;
            run += c;
        }
    }
}

// ---------------------------------------------------------------------------
// Build 3 (R8-proven): partition edges into buckets. Staging record
// (col, v0, v1, row) lands in the x1 region (dead until spmm layer 0).
__global__ __launch_bounds__(256) void partition_kernel(
    const int4*   __restrict__ rows4,
    const int4*   __restrict__ cols4,
    const float4* __restrict__ vals4,
    const float4* __restrict__ u04,
    const float4* __restrict__ u14,
    const int*    __restrict__ h,
    uint4*        __restrict__ staging) {
    __shared__ int cur[NBUCK];
    int p = blockIdx.x;
    int t = threadIdx.x;
    const int* hp = h + p * NBUCK;
    for (int i = t; i < NBUCK; i += 256) cur[i] = hp[i];
    __syncthreads();

    int i0 = p * CHUNK4;
    int i1 = i0 + CHUNK4;
    if (i1 > N_EDGES / 4) i1 = N_EDGES / 4;
    for (int i = i0 + t; i < i1; i += 256) {
        int4   r  = rows4[i];
        int4   c  = cols4[i];
        float4 v  = vals4[i];
        float4 u0 = u04[i];
        float4 u1 = u14[i];

        int p0 = atomicAdd(&cur[r.x >> 6], 1);
        int p1 = atomicAdd(&cur[r.y >> 6], 1);
        int p2 = atomicAdd(&cur[r.z >> 6], 1);
        int p3 = atomicAdd(&cur[r.w >> 6], 1);

        uint4 rec; float vv;
        vv = v.x * INV_KEEP;
        rec.x = (unsigned)c.x;
        rec.y = __float_as_uint((u0.x + KEEP_PROB >= 1.0f) ? vv : 0.f);
        rec.z = __float_as_uint((u1.x + KEEP_PROB >= 1.0f) ? vv : 0.f);
        rec.w = (unsigned)r.x;
        staging[p0] = rec;
        vv = v.y * INV_KEEP;
        rec.x = (unsigned)c.y;
        rec.y = __float_as_uint((u0.y + KEEP_PROB >= 1.0f) ? vv : 0.f);
        rec.z = __float_as_uint((u1.y + KEEP_PROB >= 1.0f) ? vv : 0.f);
        rec.w = (unsigned)r.y;
        staging[p1] = rec;
        vv = v.z * INV_KEEP;
        rec.x = (unsigned)c.z;
        rec.y = __float_as_uint((u0.z + KEEP_PROB >= 1.0f) ? vv : 0.f);
        rec.z = __float_as_uint((u1.z + KEEP_PROB >= 1.0f) ? vv : 0.f);
        rec.w = (unsigned)r.z;
        staging[p2] = rec;
        vv = v.w * INV_KEEP;
        rec.x = (unsigned)c.w;
        rec.y = __float_as_uint((u0.w + KEEP_PROB >= 1.0f) ? vv : 0.f);
        rec.z = __float_as_uint((u1.w + KEEP_PROB >= 1.0f) ? vv : 0.f);
        rec.w = (unsigned)r.w;
        staging[p3] = rec;
    }
}

// ---------------------------------------------------------------------------
// Build 4 (R8-proven): one block per bucket. Sort by row, output SoA
// per-layer 8-B records (col|lr<<17, v) into ed0/ed1.
__global__ __launch_bounds__(256) void finalize_kernel(
    const uint4* __restrict__ staging,
    const int*   __restrict__ bbase,
    unsigned long long* __restrict__ ed0,
    unsigned long long* __restrict__ ed1) {
    __shared__ uint4 recs[MAXB];
    __shared__ int cnt[64], cur[64], part[64];
    int b = blockIdx.x;
    int t = threadIdx.x;
    int base = bbase[b];
    int size = bbase[b + 1] - base;
    bool small = (size <= MAXB);

    if (small) {
        for (int i = t; i < size; i += 256) recs[i] = staging[base + i];
    }
    if (t < 64) cnt[t] = 0;
    __syncthreads();

    for (int i = t; i < size; i += 256) {
        unsigned rw = small ? recs[i].w : staging[base + i].w;
        atomicAdd(&cnt[rw & 63], 1);
    }
    __syncthreads();

    int v = (t < 64) ? cnt[t] : 0;
    if (t < 64) part[t] = v;
    __syncthreads();
    for (int d = 1; d < 64; d <<= 1) {
        int w = (t >= d && t < 64) ? part[t - d] : 0;
        __syncthreads();
        if (t < 64) part[t] += w;
        __syncthreads();
    }
    if (t < 64) cur[t] = part[t] - v;
    __syncthreads();

    for (int i = t; i < size; i += 256) {
        uint4 r = small ? recs[i] : staging[base + i];
        unsigned lr = r.w & 63u;
        int slot = base + atomicAdd(&cur[lr], 1);
        unsigned cr = r.x | (lr << 17);     // pack local row into col word
        ed0[slot] = ((unsigned long long)r.y << 32) | cr;
        ed1[slot] = ((unsigned long long)r.z << 32) | cr;
    }
}

// ---------------------------------------------------------------------------
// SpMM: flat-balanced register-accumulation, DIRECT-GLOBAL writeback.
// Gather pattern = R8-proven 16-lane groups over row-sorted edges,
// UNCHANGED (R12 lesson: fetch pattern must not change). The 16KB accs
// tile is deleted: every row has a unique owner (group with its first
// edge), so completed rows are finalized straight to io at flush time.
// Slice-boundary rows go through tailb/partb (8KB) + a post-barrier merge:
//   - in-loop flush of a non-first row  -> row complete -> direct io write
//   - first row with mid-row start      -> partb[g], prow[g]
//   - tail row (may continue into g+1)  -> tailb[g], trow[g]
//   - merge: tailb[g] + partb[g'] for consecutive g' with prow[g']==trow[g]
// Tail rows are distinct across groups (unique ownership) -> parallel merge.
// rowdone[] marks finalized rows; a sweep zeroes/scales untouched rows
// (Poisson(12): P(no edges) ~ 6e-6). LDS 8.6KB -> ~8 blocks/CU.
__global__ __launch_bounds__(256) void spmm_flat_kernel(
    const float4* __restrict__ x_in,
    const unsigned long long* __restrict__ ed,
    const int*   __restrict__ bbase,
    float4*      __restrict__ io,
    int layer) {
    __shared__ float partb[16][64];   // boundary-prefix partials
    __shared__ float tailb[16][64];   // tail-row partials
    __shared__ int   prow[16], trow[16];
    __shared__ int   rowdone[64];
    int b = blockIdx.x;
    int t = threadIdx.x;
    int base = bbase[b];
    int size = bbase[b + 1] - base;
    int row0 = b << 6;

    if (t < 16) { prow[t] = -1; trow[t] = -1; }
    if (t < 64) rowdone[t] = 0;
    __syncthreads();

    int g   = t >> 4;                 // lane-group 0..15
    int l16 = t & 15;
    int e0 = base + ((size * g) >> 4);
    int e1 = base + ((size * (g + 1)) >> 4);
    int j0 = l16 << 2;

    // does this slice start mid-row? (prev record has same lr)
    bool partial = false;
    if (e0 < e1 && e0 > base) {
        unsigned plo = (unsigned)ALOAD_U64(&ed[e0 - 1]);
        unsigned flo = (unsigned)ALOAD_U64(&ed[e0]);
        partial = ((plo >> 17) == (flo >> 17));
    }

    float4 acc = make_float4(0.f, 0.f, 0.f, 0.f);
    int cur = -1;
    bool first = true;
    for (int e = e0; e < e1; ++e) {
        unsigned long long rec = ALOAD_U64(&ed[e]);
        unsigned lo = (unsigned)rec;
        float v = __uint_as_float((unsigned)(rec >> 32));
        int lr = (int)(lo >> 17);
        if (lr != cur) {                       // group-uniform branch
            if (cur >= 0) {
                if (first && partial) {
                    *(float4*)&partb[g][j0] = acc;
                    if (l16 == 0) prow[g] = cur;
                } else {
                    // complete owned row: finalize directly to global
                    int o = ((row0 + cur) << 4) + l16;
                    if (layer == 0) {
                        io[o] = acc;
                    } else {
                        float4 p = io[o];
                        p.x = (p.x + acc.x) * (1.0f / 3.0f);
                        p.y = (p.y + acc.y) * (1.0f / 3.0f);
                        p.z = (p.z + acc.z) * (1.0f / 3.0f);
                        p.w = (p.w + acc.w) * (1.0f / 3.0f);
                        io[o] = p;
                    }
                    if (l16 == 0) rowdone[cur] = 1;
                }
                first = false;
            }
            acc = make_float4(0.f, 0.f, 0.f, 0.f);
            cur = lr;
        }
        int c  = (int)(lo & 0x1ffffu);
        int cc = (v != 0.f) ? c : 0;          // dropped edges -> hot row 0
        float4 x = x_in[(cc << 4) + l16];
        acc.x = fmaf(v, x.x, acc.x);
        acc.y = fmaf(v, x.y, acc.y);
        acc.z = fmaf(v, x.z, acc.z);
        acc.w = fmaf(v, x.w, acc.w);
    }
    if (cur >= 0) {                            // tail flush (may continue)
        if (first && partial) {
            *(float4*)&partb[g][j0] = acc;
            if (l16 == 0) prow[g] = cur;
        } else {
            *(float4*)&tailb[g][j0] = acc;
            if (l16 == 0) trow[g] = cur;
        }
    }
    __syncthreads();

    // merge tail rows (distinct across groups -> fully parallel):
    // successors of trow[g] are the consecutive g' > g with prow[g']==trow[g]
    {
        int r = trow[g];
        if (r >= 0) {
            float4 s = *(const float4*)&tailb[g][j0];
            for (int g2 = g + 1; g2 < 16 && prow[g2] == r; ++g2) {
                const float* p = &partb[g2][j0];
                s.x += p[0]; s.y += p[1]; s.z += p[2]; s.w += p[3];
            }
            int o = ((row0 + r) << 4) + l16;
            if (layer == 0) {
                io[o] = s;
            } else {
                float4 p = io[o];
                p.x = (p.x + s.x) * (1.0f / 3.0f);
                p.y = (p.y + s.y) * (1.0f / 3.0f);
                p.z = (p.z + s.z) * (1.0f / 3.0f);
                p.w = (p.w + s.w) * (1.0f / 3.0f);
                io[o] = p;
            }
            if (l16 == 0) rowdone[r] = 1;
        }
    }
    __syncthreads();

    // sweep: rows never finalized (no edges / size==0 buckets)
    #pragma unroll
    for (int i = 0; i < 4; ++i) {
        int idx = i * 256 + t;        // 0..1023 granules
        int lr = idx >> 4;
        int gg = idx & 15;
        int row = row0 + lr;
        if (row < N_NODES && !rowdone[lr]) {
            int o = (row << 4) + gg;
            if (layer == 0) {
                io[o] = make_float4(0.f, 0.f, 0.f, 0.f);
            } else {
                float4 p = io[o];
                p.x *= (1.0f / 3.0f); p.y *= (1.0f / 3.0f);
                p.z *= (1.0f / 3.0f); p.w *= (1.0f / 3.0f);
                io[o] = p;
            }
        }
    }
}

// ---------------------------------------------------------------------------
// out[n,j] = b[j] + sum_k emb[n,k]*W[j,k] + x1[n,j]
// Register-blocked: 64 nodes/block, 4x4 tile/thread; launch_bounds(256,4)
// caps VGPR at 128 (R3 lesson). R10 lesson: keep SEPARATE from spmm.
#define FMA4(A, E, WV) \
    A.x = fmaf(E, WV.x, A.x); A.y = fmaf(E, WV.y, A.y); \
    A.z = fmaf(E, WV.z, A.z); A.w = fmaf(E, WV.w, A.w);

__global__ __launch_bounds__(256, 4) void fc_add_kernel(
    const float* __restrict__ emb,
    const float* __restrict__ W,
    const float* __restrict__ b,
    const float* __restrict__ x1,
    float*       __restrict__ out) {
    __shared__ float Wt[D * 68];    // Wt[k][j] = W[j][k], row pad 68
    __shared__ float Es[64 * 68];   // Es[n][k],           row pad 68

    int t = threadIdx.x;
    int n0 = blockIdx.x * 64;

    #pragma unroll
    for (int i = 0; i < 16; ++i) {
        int idx = i * 256 + t;          // = j*64 + k
        Wt[(idx & 63) * 68 + (idx >> 6)] = W[idx];
    }
    #pragma unroll
    for (int i = 0; i < 4; ++i) {
        int idx4 = i * 256 + t;
        int n = idx4 >> 4;              // 0..63
        int k0 = (idx4 & 15) * 4;
        float4 v = make_float4(0.f, 0.f, 0.f, 0.f);
        if (n0 + n < N_NODES) v = *(const float4*)&emb[(n0 + n) * D + k0];
        *(float4*)&Es[n * 68 + k0] = v;
    }
    __syncthreads();

    int tj = t & 15;                    // j-group: j0 = 4*tj
    int tn = t >> 4;                    // node-group: nodes 4*tn .. 4*tn+3
    int j0 = tj * 4;

    float4 bb = *(const float4*)&b[j0];
    float4 acc[4];
    #pragma unroll
    for (int i = 0; i < 4; ++i) acc[i] = bb;

    const float* es = &Es[(tn * 4) * 68];
    #pragma unroll 4
    for (int kc = 0; kc < 16; ++kc) {
        int k = kc * 4;
        float4 w0 = *(const float4*)&Wt[(k + 0) * 68 + j0];
        float4 w1 = *(const float4*)&Wt[(k + 1) * 68 + j0];
        float4 w2 = *(const float4*)&Wt[(k + 2) * 68 + j0];
        float4 w3 = *(const float4*)&Wt[(k + 3) * 68 + j0];
        float4 e0 = *(const float4*)&es[0 * 68 + k];
        float4 e1 = *(const float4*)&es[1 * 68 + k];
        float4 e2 = *(const float4*)&es[2 * 68 + k];
        float4 e3 = *(const float4*)&es[3 * 68 + k];
        FMA4(acc[0], e0.x, w0); FMA4(acc[0], e0.y, w1);
        FMA4(acc[0], e0.z, w2); FMA4(acc[0], e0.w, w3);
        FMA4(acc[1], e1.x, w0); FMA4(acc[1], e1.y, w1);
        FMA4(acc[1], e1.z, w2); FMA4(acc[1], e1.w, w3);
        FMA4(acc[2], e2.x, w0); FMA4(acc[2], e2.y, w1);
        FMA4(acc[2], e2.z, w2); FMA4(acc[2], e2.w, w3);
        FMA4(acc[3], e3.x, w0); FMA4(acc[3], e3.y, w1);
        FMA4(acc[3], e3.z, w2); FMA4(acc[3], e3.w, w3);
    }

    #pragma unroll
    for (int i = 0; i < 4; ++i) {
        int n = n0 + tn * 4 + i;
        if (n < N_NODES) {
            float4 p = *(const float4*)&x1[n * D + j0];
            float4 a = acc[i];
            a.x += p.x; a.y += p.y; a.z += p.z; a.w += p.w;
            *(float4*)&out[n * D + j0] = a;
        }
    }
}

// ---------------------------------------------------------------------------
// Fallback (atomic path, replay-proven) if ws too small
__global__ __launch_bounds__(256) void spmm_atomic_kernel(
    const float* __restrict__ x_in,
    const float* __restrict__ vals,
    const float* __restrict__ drop_u,
    const int*   __restrict__ rows,
    const int*   __restrict__ cols,
    float*       __restrict__ x_out) {
    int wave = (blockIdx.x * 256 + threadIdx.x) >> 6;
    int lane = threadIdx.x & 63;
    if (wave >= N_EDGES) return;
    float u = drop_u[wave];
    if (u + KEEP_PROB < 1.0f) return;
    float v = vals[wave] * INV_KEEP;
    atomicAdd(&x_out[rows[wave] * D + lane], v * x_in[cols[wave] * D + lane]);
}

__global__ __launch_bounds__(256) void scale_kernel(float4* __restrict__ p, int n4) {
    int i = blockIdx.x * 256 + threadIdx.x;
    if (i < n4) {
        float4 v = p[i];
        v.x *= (1.f/3.f); v.y *= (1.f/3.f); v.z *= (1.f/3.f); v.w *= (1.f/3.f);
        p[i] = v;
    }
}

// ---------------------------------------------------------------------------
extern "C" void kernel_launch(void* const* d_in, const int* in_sizes, int n_in,
                              void* d_out, int out_size, void* d_ws, size_t ws_size,
                              hipStream_t stream) {
    const float* all_emb = (const float*)d_in[0];
    const float* W       = (const float*)d_in[1];
    const float* b       = (const float*)d_in[2];
    const float* vals    = (const float*)d_in[3];
    const float* drop_u  = (const float*)d_in[4];   // [2, E]
    const int*   rows    = (const int*)d_in[5];
    const int*   cols    = (const int*)d_in[6];

    float* out = (float*)d_out;

    // workspace layout (R8-proven):
    //   [0, 25.6M)       x1 output; staging records live in [0, 19.2M) and
    //                    h[PPART][NBUCK] at +19.2M (both dead before spmm-0
    //                    overwrites the region with x1)
    //   [26.0M, 35.6M)   ed0 — layer-0 SoA 8-B edge records
    //   [35.6M, 45.2M)   ed1 — layer-1 SoA 8-B edge records
    //   then total[], bbase[]
    char* ws = (char*)d_ws;
    float* x1       = (float*)(ws);
    uint4* staging  = (uint4*)(ws);
    int*   h        = (int*)  (ws + 19200000);            // 1,601,536 B
    unsigned long long* ed0 = (unsigned long long*)(ws + 26000064);  // 9.6 MB
    unsigned long long* ed1 = (unsigned long long*)(ws + 35600064);  // 9.6 MB
    int*   total    = (int*)  (ws + 45200064);            // 6,256 B
    int*   bbase    = (int*)  (ws + 45206320);            // 6,272 B
    const size_t WS_NEEDED = 45406528;   // unchanged (proven capacity)

    const int n4 = N_NODES * D / 4;
    const int zb = (n4 + 255) / 256;
    const int fc_blocks = (N_NODES + 63) / 64;            // 1563

    if (ws_size >= WS_NEEDED) {
        bucket_hist_kernel<<<PPART, 256, 0, stream>>>((const int4*)rows, h);
        sum_kernel<<<NB64, 256, 0, stream>>>(h, total);
        bucket_scan_kernel<<<1, 256, 0, stream>>>(total, bbase);
        rebase_kernel<<<NB64, 256, 0, stream>>>(h, bbase);
        partition_kernel<<<PPART, 256, 0, stream>>>(
            (const int4*)rows, (const int4*)cols, (const float4*)vals,
            (const float4*)drop_u, (const float4*)(drop_u + N_EDGES),
            h, staging);
        finalize_kernel<<<NBUCK, 256, 0, stream>>>(staging, bbase, ed0, ed1);
        // layer 0: x1 = A1 @ all_emb   (overwrites staging/h region)
        spmm_flat_kernel<<<NBUCK, 256, 0, stream>>>(
            (const float4*)all_emb, ed0, bbase, (float4*)x1, 0);
        // out = fc(all_emb) + x1
        fc_add_kernel<<<fc_blocks, 256, 0, stream>>>(all_emb, W, b, x1, out);
        // layer 1 (fused /3): out = (out + A2 @ x1) / 3
        spmm_flat_kernel<<<NBUCK, 256, 0, stream>>>(
            (const float4*)x1, ed1, bbase, (float4*)out, 1);
    } else {
        // fallback: proven atomic path
        const int spmm_blocks = (N_EDGES + 3) / 4;
        zero_kernel<<<zb, 256, 0, stream>>>((float4*)x1, n4);
        spmm_atomic_kernel<<<spmm_blocks, 256, 0, stream>>>(all_emb, vals, drop_u,
                                                            rows, cols, x1);
        fc_add_kernel<<<fc_blocks, 256, 0, stream>>>(all_emb, W, b, x1, out);
        spmm_atomic_kernel<<<spmm_blocks, 256, 0, stream>>>(x1, vals,
                                                            drop_u + N_EDGES,
                                                            rows, cols, out);
        scale_kernel<<<zb, 256, 0, stream>>>((float4*)out, n4);
    }
}